// Round 1
// baseline (73.605 us; speedup 1.0000x reference)
//
#include <hip/hip_runtime.h>
#include <hip/hip_bf16.h>

typedef __attribute__((ext_vector_type(8))) __bf16 bf16x8;
typedef __attribute__((ext_vector_type(4))) float f32x4;

#define B_M 256
#define K_D 512
#define N_C 100000
#define BN 64
#define BK 64
#define NBLK ((N_C + BN - 1) / BN)   /* 1563 */

__device__ __forceinline__ unsigned short f2bf(float x) {
  unsigned int u = __float_as_uint(x);
  u += 0x7fffu + ((u >> 16) & 1u);          // round-to-nearest-even
  return (unsigned short)(u >> 16);
}

// ---------------- kernel 1: row-normalize emb -> bf16 ff ----------------
__global__ __launch_bounds__(256) void norm_kernel(const float* __restrict__ emb,
                                                   unsigned short* __restrict__ ff) {
  const int row = blockIdx.x;
  const int t = threadIdx.x;
  float a = emb[row * K_D + t];
  float b = emb[row * K_D + t + 256];
  float ss = a * a + b * b;
  #pragma unroll
  for (int o = 32; o > 0; o >>= 1) ss += __shfl_down(ss, o, 64);
  __shared__ float red[4];
  const int wid = t >> 6, lane = t & 63;
  if (lane == 0) red[wid] = ss;
  __syncthreads();
  float tot = red[0] + red[1] + red[2] + red[3];
  float rn = 1.0f / fmaxf(sqrtf(tot), 1e-12f);
  ff[row * K_D + t]       = f2bf(a * rn);
  ff[row * K_D + t + 256] = f2bf(b * rn);
}

// ---------------- kernel 2: fused GEMM + circle-loss partial reduce ----------------
__global__ __launch_bounds__(512) void gemm_loss_kernel(const unsigned short* __restrict__ ff,
                                                        const float* __restrict__ W,
                                                        const int* __restrict__ labels,
                                                        double* __restrict__ partials) {
  __shared__ __align__(16) unsigned short As[B_M * BK];  // 32 KB, XOR-swizzled
  __shared__ __align__(16) unsigned short Bs[BN * BK];   //  8 KB, XOR-swizzled
  __shared__ int lbl[B_M];
  __shared__ double red[16];

  const int tid = threadIdx.x;
  const int wid = tid >> 6;
  const int lane = tid & 63;
  const int n0 = blockIdx.x * BN;

  if (tid < B_M) lbl[tid] = labels[tid];

  f32x4 acc[2][4] = {};

  const int wrow = wid * 32;
  const int l15 = lane & 15;
  const int lhi = lane >> 4;

  // B staging geometry: thread -> (col, 8-float chunk)
  const int bcol = tid >> 3;              // 0..63
  const int bk8  = tid & 7;               // 0..7
  const long long jrow = (long long)n0 + bcol;

  for (int kk = 0; kk < K_D / BK; ++kk) {
    if (kk) __syncthreads();
    // --- stage A: 256x64 bf16 from ff (L2-resident), swizzled ---
    #pragma unroll
    for (int it = 0; it < 4; ++it) {
      int idx = it * 512 + tid;           // 0..2047 chunks of 8 bf16
      int row = idx >> 3;
      int kc  = idx & 7;
      uint4 v = *reinterpret_cast<const uint4*>(ff + row * K_D + kk * BK + kc * 8);
      int off = (row * 128 + kc * 16) ^ ((row & 7) << 4);
      *reinterpret_cast<uint4*>(reinterpret_cast<char*>(As) + off) = v;
    }
    // --- stage B: 64x64 f32 -> bf16, swizzled ---
    {
      float4 f0 = {0.f, 0.f, 0.f, 0.f}, f1 = {0.f, 0.f, 0.f, 0.f};
      if (jrow < N_C) {
        const float* gp = W + jrow * K_D + kk * BK + bk8 * 8;
        f0 = *reinterpret_cast<const float4*>(gp);
        f1 = *reinterpret_cast<const float4*>(gp + 4);
      }
      union { unsigned short us[8]; uint4 v; } pk;
      pk.us[0] = f2bf(f0.x); pk.us[1] = f2bf(f0.y); pk.us[2] = f2bf(f0.z); pk.us[3] = f2bf(f0.w);
      pk.us[4] = f2bf(f1.x); pk.us[5] = f2bf(f1.y); pk.us[6] = f2bf(f1.z); pk.us[7] = f2bf(f1.w);
      int off = (bcol * 128 + bk8 * 16) ^ ((bcol & 7) << 4);
      *reinterpret_cast<uint4*>(reinterpret_cast<char*>(Bs) + off) = pk.v;
    }
    __syncthreads();

    // --- fragments + MFMA ---
    bf16x8 afr[2][2], bfr[4][2];
    #pragma unroll
    for (int fm = 0; fm < 2; ++fm)
      #pragma unroll
      for (int ks = 0; ks < 2; ++ks) {
        int row = wrow + fm * 16 + l15;
        int off = (row * 128 + ks * 64 + lhi * 16) ^ ((row & 7) << 4);
        afr[fm][ks] = *reinterpret_cast<const bf16x8*>(reinterpret_cast<const char*>(As) + off);
      }
    #pragma unroll
    for (int fn = 0; fn < 4; ++fn)
      #pragma unroll
      for (int ks = 0; ks < 2; ++ks) {
        int col = fn * 16 + l15;
        int off = (col * 128 + ks * 64 + lhi * 16) ^ ((col & 7) << 4);
        bfr[fn][ks] = *reinterpret_cast<const bf16x8*>(reinterpret_cast<const char*>(Bs) + off);
      }
    #pragma unroll
    for (int fm = 0; fm < 2; ++fm)
      #pragma unroll
      for (int fn = 0; fn < 4; ++fn)
        #pragma unroll
        for (int ks = 0; ks < 2; ++ks)
          acc[fm][fn] = __builtin_amdgcn_mfma_f32_16x16x32_bf16(afr[fm][ks], bfr[fn][ks], acc[fm][fn], 0, 0, 0);
  }

  // --- fused epilogue: circle-loss terms ---
  float sn_local = 0.0f;
  double sp_local = 0.0;
  #pragma unroll
  for (int fm = 0; fm < 2; ++fm)
    #pragma unroll
    for (int fn = 0; fn < 4; ++fn)
      #pragma unroll
      for (int r = 0; r < 4; ++r) {
        int row = wrow + fm * 16 + lhi * 4 + r;   // C/D: col=lane&15, row=(lane>>4)*4+reg
        int j = n0 + fn * 16 + l15;
        float v = acc[fm][fn][r];
        if (j < N_C) {
          if (j == lbl[row]) {
            double alpha = fmax(1.25 - (double)v, 0.0);     // clamp(Op - sp, 0)
            sp_local += exp(-64.0 * alpha * ((double)v - 0.75));
          } else {
            float an = fmaxf(v + 0.25f, 0.0f);              // clamp(sn + m, 0)
            sn_local += __expf(64.0f * an * (v - 0.25f));
          }
        }
      }

  double sn_d = (double)sn_local;
  #pragma unroll
  for (int o = 32; o > 0; o >>= 1) {
    sn_d     += __shfl_down(sn_d, o, 64);
    sp_local += __shfl_down(sp_local, o, 64);
  }
  if (lane == 0) { red[wid] = sn_d; red[8 + wid] = sp_local; }
  __syncthreads();
  if (tid == 0) {
    double a = 0.0, b = 0.0;
    #pragma unroll
    for (int i = 0; i < 8; ++i) { a += red[i]; b += red[8 + i]; }
    partials[blockIdx.x] = a;          // sn partial
    partials[NBLK + blockIdx.x] = b;   // sp partial
  }
}

// ---------------- kernel 3: final reduce + log1p ----------------
__global__ __launch_bounds__(512) void finalize_kernel(const double* __restrict__ partials,
                                                       float* __restrict__ out) {
  const int t = threadIdx.x;
  double sn = 0.0, sp = 0.0;
  for (int i = t; i < NBLK; i += 512) { sn += partials[i]; sp += partials[NBLK + i]; }
  #pragma unroll
  for (int o = 32; o > 0; o >>= 1) { sn += __shfl_down(sn, o, 64); sp += __shfl_down(sp, o, 64); }
  __shared__ double red[16];
  const int wid = t >> 6, lane = t & 63;
  if (lane == 0) { red[wid] = sn; red[8 + wid] = sp; }
  __syncthreads();
  if (t == 0) {
    double a = 0.0, b = 0.0;
    for (int i = 0; i < 8; ++i) { a += red[i]; b += red[8 + i]; }
    out[0] = (float)log1p(a * b);
  }
}

extern "C" void kernel_launch(void* const* d_in, const int* in_sizes, int n_in,
                              void* d_out, int out_size, void* d_ws, size_t ws_size,
                              hipStream_t stream) {
  // inputs: 0=x (unused), 1=labels (int), 2=emb (f32), 3=W (f32)
  const int*   labels = (const int*)d_in[1];
  const float* emb    = (const float*)d_in[2];
  const float* W      = (const float*)d_in[3];
  float* out = (float*)d_out;

  unsigned short* ff = (unsigned short*)d_ws;                              // 256*512*2 = 262144 B
  double* partials = (double*)((char*)d_ws + (size_t)B_M * K_D * 2);       // 2*1563*8 B

  norm_kernel<<<B_M, 256, 0, stream>>>(emb, ff);
  gemm_loss_kernel<<<NBLK, 512, 0, stream>>>(ff, W, labels, partials);
  finalize_kernel<<<1, 512, 0, stream>>>(partials, out);
}